// Round 1
// baseline (125.155 us; speedup 1.0000x reference)
//
#include <hip/hip_runtime.h>
#include <hip/hip_bf16.h>

// Problem constants (from reference)
#define BATCH 4096
#define D_X   1024
#define D_Y   512

constexpr float SIGMA_INV = 0.1f;    // 1/10.0
constexpr float EPS_THR   = 46.0f;

constexpr int BM = 128;              // tile M = tile N
constexpr int BK = 64;               // K step
constexpr int NT = BATCH / BM;       // 32 tile-rows
constexpr int NBLK = NT * (NT + 1) / 2;  // 528 upper-triangular tiles

typedef __bf16 bf16x8 __attribute__((ext_vector_type(8)));
typedef float  f32x4  __attribute__((ext_vector_type(4)));
typedef unsigned short u16x8 __attribute__((ext_vector_type(8)));

__device__ __forceinline__ unsigned short f32_to_bf16_bits(float f) {
    unsigned int u = __builtin_bit_cast(unsigned int, f);
    // round-to-nearest-even
    unsigned int r = (u + 0x7FFFu + ((u >> 16) & 1u)) >> 16;
    return (unsigned short)r;
}

// ---------------------------------------------------------------------------
// Kernel 1: row squared-norms of x and y -> ws
// ---------------------------------------------------------------------------
__global__ void norms_kernel(const float* __restrict__ x,
                             const float* __restrict__ y,
                             float* __restrict__ sqx,
                             float* __restrict__ sqy) {
    int row = blockIdx.x;
    int t   = threadIdx.x;  // 64 threads = 1 wave

    const float4* xr = (const float4*)(x + (size_t)row * D_X);
    float sx = 0.f;
#pragma unroll
    for (int i = 0; i < D_X / 4 / 64; ++i) {
        float4 v = xr[t + i * 64];
        sx += v.x * v.x + v.y * v.y + v.z * v.z + v.w * v.w;
    }
    const float4* yr = (const float4*)(y + (size_t)row * D_Y);
    float sy = 0.f;
#pragma unroll
    for (int i = 0; i < D_Y / 4 / 64; ++i) {
        float4 v = yr[t + i * 64];
        sy += v.x * v.x + v.y * v.y + v.z * v.z + v.w * v.w;
    }
#pragma unroll
    for (int off = 32; off > 0; off >>= 1) {
        sx += __shfl_down(sx, off, 64);
        sy += __shfl_down(sy, off, 64);
    }
    if (t == 0) {
        sqx[row] = sx;
        sqy[row] = sy;
    }
}

// ---------------------------------------------------------------------------
// Stage a 128x64 f32 tile -> bf16 LDS tile with 16B-slot XOR swizzle.
// dst is [128 rows][8 slots of 16B]; slot s of row r lives at s ^ (r & 7).
// ---------------------------------------------------------------------------
__device__ __forceinline__ void stage_tile(const float* __restrict__ src, int ld,
                                           int base_row, int k0,
                                           u16x8* __restrict__ dst, int tid) {
#pragma unroll
    for (int it = 0; it < 2; ++it) {
        int u   = tid + it * 256;      // 0..511
        int row = u >> 2;              // 0..127
        int q   = u & 3;               // 16-float chunk within the 64-wide row
        const float4* p = (const float4*)(src + (size_t)(base_row + row) * ld + k0 + q * 16);
        float4 f0 = p[0], f1 = p[1], f2 = p[2], f3 = p[3];
        u16x8 lo, hi;
        lo[0] = f32_to_bf16_bits(f0.x); lo[1] = f32_to_bf16_bits(f0.y);
        lo[2] = f32_to_bf16_bits(f0.z); lo[3] = f32_to_bf16_bits(f0.w);
        lo[4] = f32_to_bf16_bits(f1.x); lo[5] = f32_to_bf16_bits(f1.y);
        lo[6] = f32_to_bf16_bits(f1.z); lo[7] = f32_to_bf16_bits(f1.w);
        hi[0] = f32_to_bf16_bits(f2.x); hi[1] = f32_to_bf16_bits(f2.y);
        hi[2] = f32_to_bf16_bits(f2.z); hi[3] = f32_to_bf16_bits(f2.w);
        hi[4] = f32_to_bf16_bits(f3.x); hi[5] = f32_to_bf16_bits(f3.y);
        hi[6] = f32_to_bf16_bits(f3.z); hi[7] = f32_to_bf16_bits(f3.w);
        int swz = row & 7;
        dst[row * 8 + ((2 * q) ^ swz)]     = lo;
        dst[row * 8 + ((2 * q + 1) ^ swz)] = hi;
    }
}

// ---------------------------------------------------------------------------
// Kernel 2: fused Gram(x), Gram(y) -> masked heat-kernel loss, one atomicAdd
// per block. Upper-triangular tile enumeration; off-diagonal tiles doubled.
// ---------------------------------------------------------------------------
__global__ void __launch_bounds__(256, 2)
graph_loss_kernel(const float* __restrict__ x, const float* __restrict__ y,
                  const float* __restrict__ sqx, const float* __restrict__ sqy,
                  float* __restrict__ out) {
    __shared__ u16x8 As[BM * 8];     // 16 KB, swizzled bf16 [128][64]
    __shared__ u16x8 Bs[BM * 8];     // 16 KB
    __shared__ float snxA[BM], snxB[BM], snyA[BM], snyB[BM];
    __shared__ float wsum[4];

    const int tid  = threadIdx.x;
    const int lane = tid & 63;
    const int wid  = tid >> 6;
    const int wr   = wid >> 1;       // wave row (0..1)
    const int wc   = wid & 1;        // wave col (0..1)
    const int lrow = lane & 15;      // fragment row/col index
    const int kgrp = lane >> 4;      // k-group 0..3

    // triangular tile mapping: blockIdx.x -> (bi, bj), bj >= bi
    int t = blockIdx.x, bi = 0;
    while (t >= NT - bi) { t -= NT - bi; ++bi; }
    const int bj = bi + t;
    const int iA = bi * BM;
    const int iB = bj * BM;

    if (tid < BM) {
        snxA[tid] = sqx[iA + tid];
        snyA[tid] = sqy[iA + tid];
        snxB[tid] = sqx[iB + tid];
        snyB[tid] = sqy[iB + tid];
    }

    f32x4 accX[4][4] = {};
    f32x4 accY[4][4] = {};

    // ---- Phase X: Gx = X_A . X_B^T over K = 1024 ----
    for (int kt = 0; kt < D_X / BK; ++kt) {
        __syncthreads();
        stage_tile(x, D_X, iA, kt * BK, As, tid);
        stage_tile(x, D_X, iB, kt * BK, Bs, tid);
        __syncthreads();
#pragma unroll
        for (int ks = 0; ks < 2; ++ks) {
            bf16x8 a[4], b[4];
#pragma unroll
            for (int m = 0; m < 4; ++m) {
                int row  = wr * 64 + m * 16 + lrow;
                int slot = (ks * 4 + kgrp) ^ (row & 7);
                a[m] = __builtin_bit_cast(bf16x8, As[row * 8 + slot]);
            }
#pragma unroll
            for (int n = 0; n < 4; ++n) {
                int row  = wc * 64 + n * 16 + lrow;
                int slot = (ks * 4 + kgrp) ^ (row & 7);
                b[n] = __builtin_bit_cast(bf16x8, Bs[row * 8 + slot]);
            }
#pragma unroll
            for (int m = 0; m < 4; ++m)
#pragma unroll
                for (int n = 0; n < 4; ++n)
                    accX[m][n] = __builtin_amdgcn_mfma_f32_16x16x32_bf16(
                        a[m], b[n], accX[m][n], 0, 0, 0);
        }
    }

    // ---- Phase Y: Gy = Y_A . Y_B^T over K = 512 ----
    for (int kt = 0; kt < D_Y / BK; ++kt) {
        __syncthreads();
        stage_tile(y, D_Y, iA, kt * BK, As, tid);
        stage_tile(y, D_Y, iB, kt * BK, Bs, tid);
        __syncthreads();
#pragma unroll
        for (int ks = 0; ks < 2; ++ks) {
            bf16x8 a[4], b[4];
#pragma unroll
            for (int m = 0; m < 4; ++m) {
                int row  = wr * 64 + m * 16 + lrow;
                int slot = (ks * 4 + kgrp) ^ (row & 7);
                a[m] = __builtin_bit_cast(bf16x8, As[row * 8 + slot]);
            }
#pragma unroll
            for (int n = 0; n < 4; ++n) {
                int row  = wc * 64 + n * 16 + lrow;
                int slot = (ks * 4 + kgrp) ^ (row & 7);
                b[n] = __builtin_bit_cast(bf16x8, Bs[row * 8 + slot]);
            }
#pragma unroll
            for (int m = 0; m < 4; ++m)
#pragma unroll
                for (int n = 0; n < 4; ++n)
                    accY[m][n] = __builtin_amdgcn_mfma_f32_16x16x32_bf16(
                        a[m], b[n], accY[m][n], 0, 0, 0);
        }
    }

    // ---- Epilogue: d2 -> dx, dy -> masked heat-kernel contribution ----
    // C/D layout (m89, verified): col = lane&15, row = (lane>>4)*4 + reg
    float local = 0.f;
#pragma unroll
    for (int m = 0; m < 4; ++m) {
#pragma unroll
        for (int n = 0; n < 4; ++n) {
            int col   = wc * 64 + n * 16 + lrow;
            float sxj = snxB[col];
            float syj = snyB[col];
#pragma unroll
            for (int r = 0; r < 4; ++r) {
                int rowi  = wr * 64 + m * 16 + kgrp * 4 + r;
                float d2x = snxA[rowi] + sxj - 2.f * accX[m][n][r];
                float dxv = sqrtf(fmaxf(d2x, 1e-12f));
                float d2y = snyA[rowi] + syj - 2.f * accY[m][n][r];
                float dyv = sqrtf(fmaxf(d2y, 1e-12f));
                int gi = iA + rowi, gj = iB + col;
                bool keep = (gi != gj) && (dxv <= EPS_THR);
                float contrib = __expf(-dxv * SIGMA_INV) * dyv;
                local += keep ? contrib : 0.f;
            }
        }
    }
    if (bi != bj) local *= 2.f;   // upper-triangular doubling

#pragma unroll
    for (int off = 32; off > 0; off >>= 1)
        local += __shfl_down(local, off, 64);
    if (lane == 0) wsum[wid] = local;
    __syncthreads();
    if (tid == 0)
        atomicAdd(out, wsum[0] + wsum[1] + wsum[2] + wsum[3]);
}

// ---------------------------------------------------------------------------
extern "C" void kernel_launch(void* const* d_in, const int* in_sizes, int n_in,
                              void* d_out, int out_size, void* d_ws, size_t ws_size,
                              hipStream_t stream) {
    const float* x = (const float*)d_in[0];
    const float* y = (const float*)d_in[1];
    float* out = (float*)d_out;
    float* sqx = (float*)d_ws;          // BATCH floats
    float* sqy = sqx + BATCH;           // BATCH floats  (32 KB total)

    // d_out is poisoned before timing and we accumulate with atomics -> zero it.
    hipMemsetAsync(d_out, 0, sizeof(float) * (size_t)out_size, stream);

    norms_kernel<<<BATCH, 64, 0, stream>>>(x, y, sqx, sqy);
    graph_loss_kernel<<<NBLK, 256, 0, stream>>>(x, y, sqx, sqy, out);
}

// Round 2
// 78.451 us; speedup vs baseline: 1.5953x; 1.5953x over previous
//
#include <hip/hip_runtime.h>
#include <hip/hip_bf16.h>
#include <stdint.h>

// Problem constants (from reference)
#define BATCH 4096
#define D_X   1024
#define D_Y   512

constexpr float SIGMA_INV = 0.1f;    // 1/10.0
constexpr float EPS_THR   = 46.0f;

constexpr int BM = 128;              // tile M = tile N
constexpr int NT = BATCH / BM;       // 32 tile-rows
constexpr int NBLK = NT * (NT + 1) / 2;  // 528 upper-triangular tiles

constexpr int XSLOTS = D_X / 8;      // 128 16B-slots (8 bf16) per x row
constexpr int YSLOTS = D_Y / 8;      // 64 slots per y row

typedef __bf16 bf16x8 __attribute__((ext_vector_type(8)));
typedef float  f32x4  __attribute__((ext_vector_type(4)));
typedef unsigned short u16x8 __attribute__((ext_vector_type(8)));

__device__ __forceinline__ unsigned short f32_to_bf16_bits(float f) {
    unsigned int u = __builtin_bit_cast(unsigned int, f);
    unsigned int r = (u + 0x7FFFu + ((u >> 16) & 1u)) >> 16;  // RNE
    return (unsigned short)r;
}

// ===========================================================================
// FAST PATH
// ===========================================================================

// ---------------------------------------------------------------------------
// Kernel 1: f32 -> bf16 conversion with PRE-SWIZZLED slot layout + row norms.
// Stored slot s of row r holds original slot (s&~7)|((s&7)^(r&7)), so that a
// LINEAR global_load_lds stage produces the XOR-swizzled LDS tile directly
// (swizzle-the-source pattern; LDS dest must stay linear for global_load_lds).
// One block (192 thr) per row: t<128 -> x slots, t in [128,192) -> y slots.
// ---------------------------------------------------------------------------
__global__ void __launch_bounds__(192)
convert_kernel(const float* __restrict__ x, const float* __restrict__ y,
               u16x8* __restrict__ xb, u16x8* __restrict__ yb,
               float* __restrict__ sqx, float* __restrict__ sqy) {
    __shared__ float part[2];
    const int row = blockIdx.x;
    const int t   = threadIdx.x;
    const int lane = t & 63;
    const int wid  = t >> 6;

    float ss = 0.f;
    if (t < 128) {
        const float4* p = (const float4*)(x + (size_t)row * D_X + t * 8);
        float4 a = p[0], b = p[1];
        ss = a.x*a.x + a.y*a.y + a.z*a.z + a.w*a.w
           + b.x*b.x + b.y*b.y + b.z*b.z + b.w*b.w;
        u16x8 v;
        v[0] = f32_to_bf16_bits(a.x); v[1] = f32_to_bf16_bits(a.y);
        v[2] = f32_to_bf16_bits(a.z); v[3] = f32_to_bf16_bits(a.w);
        v[4] = f32_to_bf16_bits(b.x); v[5] = f32_to_bf16_bits(b.y);
        v[6] = f32_to_bf16_bits(b.z); v[7] = f32_to_bf16_bits(b.w);
        int s = (t & ~7) | ((t & 7) ^ (row & 7));
        xb[(size_t)row * XSLOTS + s] = v;
    } else {
        int o = t - 128;  // 0..63
        const float4* p = (const float4*)(y + (size_t)row * D_Y + o * 8);
        float4 a = p[0], b = p[1];
        ss = a.x*a.x + a.y*a.y + a.z*a.z + a.w*a.w
           + b.x*b.x + b.y*b.y + b.z*b.z + b.w*b.w;
        u16x8 v;
        v[0] = f32_to_bf16_bits(a.x); v[1] = f32_to_bf16_bits(a.y);
        v[2] = f32_to_bf16_bits(a.z); v[3] = f32_to_bf16_bits(a.w);
        v[4] = f32_to_bf16_bits(b.x); v[5] = f32_to_bf16_bits(b.y);
        v[6] = f32_to_bf16_bits(b.z); v[7] = f32_to_bf16_bits(b.w);
        int s = (o & ~7) | ((o & 7) ^ (row & 7));
        yb[(size_t)row * YSLOTS + s] = v;
    }
#pragma unroll
    for (int off = 32; off > 0; off >>= 1)
        ss += __shfl_down(ss, off, 64);
    if (lane == 0) {
        if (wid < 2) part[wid] = ss;
        else         sqy[row] = ss;
    }
    __syncthreads();
    if (t == 0) sqx[row] = part[0] + part[1];
}

// ---------------------------------------------------------------------------
// Async stage: 128 rows x 8 slots (16 KB) from pre-swizzled bf16 panel -> LDS,
// linear dest, 16B global_load_lds (wave-uniform LDS base + lane*16).
// ---------------------------------------------------------------------------
__device__ __forceinline__ void stage(const u16x8* __restrict__ src, int rowslots,
                                      int base_row, int kslot0,
                                      u16x8* dst, int tid) {
    const int wid = tid >> 6, lane = tid & 63;
#pragma unroll
    for (int it = 0; it < 4; ++it) {
        int u  = it * 256 + wid * 64;   // wave-uniform LDS slot base
        int ul = u + lane;
        int row = ul >> 3, slot = ul & 7;
        const u16x8* g = src + (size_t)(base_row + row) * rowslots + kslot0 + slot;
        __builtin_amdgcn_global_load_lds(
            (const uint32_t __attribute__((address_space(1)))*)g,
            (uint32_t __attribute__((address_space(3)))*)(dst + u), 16, 0, 0);
    }
}

// One K=64 step: 2 ks x 16 MFMA reading swizzled LDS tiles.
__device__ __forceinline__ void mfma_step(const u16x8* As_, const u16x8* Bs_,
                                          int wr, int wc, int lrow, int kgrp,
                                          f32x4 acc[4][4]) {
#pragma unroll
    for (int ks = 0; ks < 2; ++ks) {
        bf16x8 a[4], b[4];
#pragma unroll
        for (int m = 0; m < 4; ++m) {
            int row  = wr * 64 + m * 16 + lrow;
            int slot = (ks * 4 + kgrp) ^ (row & 7);
            a[m] = __builtin_bit_cast(bf16x8, As_[row * 8 + slot]);
        }
#pragma unroll
        for (int n = 0; n < 4; ++n) {
            int row  = wc * 64 + n * 16 + lrow;
            int slot = (ks * 4 + kgrp) ^ (row & 7);
            b[n] = __builtin_bit_cast(bf16x8, Bs_[row * 8 + slot]);
        }
#pragma unroll
        for (int m = 0; m < 4; ++m)
#pragma unroll
            for (int n = 0; n < 4; ++n)
                acc[m][n] = __builtin_amdgcn_mfma_f32_16x16x32_bf16(
                    a[m], b[n], acc[m][n], 0, 0, 0);
    }
}

// ---------------------------------------------------------------------------
// Kernel 2: fused Gram(x), Gram(y) -> masked heat-kernel loss.
// m97 structure: global_load_lds staging, 2 barriers / K-step.
// ---------------------------------------------------------------------------
__global__ void __launch_bounds__(256, 2)
graph_loss_bf16(const u16x8* __restrict__ xb, const u16x8* __restrict__ yb,
                const float* __restrict__ sqx, const float* __restrict__ sqy,
                float* __restrict__ out) {
    __shared__ u16x8 As[BM * 8];     // 16 KB swizzled bf16 [128][64]
    __shared__ u16x8 Bs[BM * 8];     // 16 KB
    __shared__ float snxA[BM], snxB[BM], snyA[BM], snyB[BM];
    __shared__ float wsum[4];

    const int tid  = threadIdx.x;
    const int lane = tid & 63;
    const int wid  = tid >> 6;
    const int wr   = wid >> 1;
    const int wc   = wid & 1;
    const int lrow = lane & 15;
    const int kgrp = lane >> 4;

    // triangular tile mapping
    int t = blockIdx.x, bi = 0;
    while (t >= NT - bi) { t -= NT - bi; ++bi; }
    const int bj = bi + t;
    const int iA = bi * BM;
    const int iB = bj * BM;
    const bool diag = (bi == bj);

    if (tid < BM) {
        snxA[tid] = sqx[iA + tid];
        snyA[tid] = sqy[iA + tid];
        snxB[tid] = sqx[iB + tid];
        snyB[tid] = sqy[iB + tid];
    }

    f32x4 accX[4][4] = {};
    f32x4 accY[4][4] = {};
    const u16x8* Bsp = diag ? As : Bs;

    // ---- Phase X: Gx over K = 1024 (16 steps) ----
    for (int kt = 0; kt < D_X / 64; ++kt) {
        __syncthreads();
        stage(xb, XSLOTS, iA, kt * 8, As, tid);
        if (!diag) stage(xb, XSLOTS, iB, kt * 8, Bs, tid);
        __syncthreads();
        mfma_step(As, Bsp, wr, wc, lrow, kgrp, accX);
    }

    // ---- Phase Y: Gy over K = 512 (8 steps) ----
    for (int kt = 0; kt < D_Y / 64; ++kt) {
        __syncthreads();
        stage(yb, YSLOTS, iA, kt * 8, As, tid);
        if (!diag) stage(yb, YSLOTS, iB, kt * 8, Bs, tid);
        __syncthreads();
        mfma_step(As, Bsp, wr, wc, lrow, kgrp, accY);
    }

    // ---- Epilogue: C/D layout col=lane&15, row=(lane>>4)*4+reg (m89) ----
    float local = 0.f;
#pragma unroll
    for (int m = 0; m < 4; ++m) {
#pragma unroll
        for (int n = 0; n < 4; ++n) {
            int col   = wc * 64 + n * 16 + lrow;
            float sxj = snxB[col];
            float syj = snyB[col];
#pragma unroll
            for (int r = 0; r < 4; ++r) {
                int rowi  = wr * 64 + m * 16 + kgrp * 4 + r;
                float d2x = snxA[rowi] + sxj - 2.f * accX[m][n][r];
                float dxv = sqrtf(fmaxf(d2x, 1e-12f));
                float d2y = snyA[rowi] + syj - 2.f * accY[m][n][r];
                float dyv = sqrtf(fmaxf(d2y, 1e-12f));
                int gi = iA + rowi, gj = iB + col;
                bool keep = (gi != gj) && (dxv <= EPS_THR);
                float contrib = __expf(-dxv * SIGMA_INV) * dyv;
                local += keep ? contrib : 0.f;
            }
        }
    }
    if (!diag) local *= 2.f;

#pragma unroll
    for (int off = 32; off > 0; off >>= 1)
        local += __shfl_down(local, off, 64);
    if (lane == 0) wsum[wid] = local;
    __syncthreads();
    if (tid == 0)
        atomicAdd(out, wsum[0] + wsum[1] + wsum[2] + wsum[3]);
}

// ===========================================================================
// FALLBACK PATH (round-1 kernels, used only if ws_size is too small)
// ===========================================================================
__global__ void norms_kernel_fb(const float* __restrict__ x,
                                const float* __restrict__ y,
                                float* __restrict__ sqx,
                                float* __restrict__ sqy) {
    int row = blockIdx.x;
    int t   = threadIdx.x;
    const float4* xr = (const float4*)(x + (size_t)row * D_X);
    float sx = 0.f;
#pragma unroll
    for (int i = 0; i < D_X / 4 / 64; ++i) {
        float4 v = xr[t + i * 64];
        sx += v.x * v.x + v.y * v.y + v.z * v.z + v.w * v.w;
    }
    const float4* yr = (const float4*)(y + (size_t)row * D_Y);
    float sy = 0.f;
#pragma unroll
    for (int i = 0; i < D_Y / 4 / 64; ++i) {
        float4 v = yr[t + i * 64];
        sy += v.x * v.x + v.y * v.y + v.z * v.z + v.w * v.w;
    }
#pragma unroll
    for (int off = 32; off > 0; off >>= 1) {
        sx += __shfl_down(sx, off, 64);
        sy += __shfl_down(sy, off, 64);
    }
    if (t == 0) { sqx[row] = sx; sqy[row] = sy; }
}

__device__ __forceinline__ void stage_tile_fb(const float* __restrict__ src, int ld,
                                              int base_row, int k0,
                                              u16x8* __restrict__ dst, int tid) {
#pragma unroll
    for (int it = 0; it < 2; ++it) {
        int u   = tid + it * 256;
        int row = u >> 2;
        int q   = u & 3;
        const float4* p = (const float4*)(src + (size_t)(base_row + row) * ld + k0 + q * 16);
        float4 f0 = p[0], f1 = p[1], f2 = p[2], f3 = p[3];
        u16x8 lo, hi;
        lo[0] = f32_to_bf16_bits(f0.x); lo[1] = f32_to_bf16_bits(f0.y);
        lo[2] = f32_to_bf16_bits(f0.z); lo[3] = f32_to_bf16_bits(f0.w);
        lo[4] = f32_to_bf16_bits(f1.x); lo[5] = f32_to_bf16_bits(f1.y);
        lo[6] = f32_to_bf16_bits(f1.z); lo[7] = f32_to_bf16_bits(f1.w);
        hi[0] = f32_to_bf16_bits(f2.x); hi[1] = f32_to_bf16_bits(f2.y);
        hi[2] = f32_to_bf16_bits(f2.z); hi[3] = f32_to_bf16_bits(f2.w);
        hi[4] = f32_to_bf16_bits(f3.x); hi[5] = f32_to_bf16_bits(f3.y);
        hi[6] = f32_to_bf16_bits(f3.z); hi[7] = f32_to_bf16_bits(f3.w);
        int swz = row & 7;
        dst[row * 8 + ((2 * q) ^ swz)]     = lo;
        dst[row * 8 + ((2 * q + 1) ^ swz)] = hi;
    }
}

__global__ void __launch_bounds__(256, 2)
graph_loss_fb(const float* __restrict__ x, const float* __restrict__ y,
              const float* __restrict__ sqx, const float* __restrict__ sqy,
              float* __restrict__ out) {
    __shared__ u16x8 As[BM * 8];
    __shared__ u16x8 Bs[BM * 8];
    __shared__ float snxA[BM], snxB[BM], snyA[BM], snyB[BM];
    __shared__ float wsum[4];

    const int tid  = threadIdx.x;
    const int lane = tid & 63;
    const int wid  = tid >> 6;
    const int wr   = wid >> 1;
    const int wc   = wid & 1;
    const int lrow = lane & 15;
    const int kgrp = lane >> 4;

    int t = blockIdx.x, bi = 0;
    while (t >= NT - bi) { t -= NT - bi; ++bi; }
    const int bj = bi + t;
    const int iA = bi * BM;
    const int iB = bj * BM;

    if (tid < BM) {
        snxA[tid] = sqx[iA + tid];
        snyA[tid] = sqy[iA + tid];
        snxB[tid] = sqx[iB + tid];
        snyB[tid] = sqy[iB + tid];
    }

    f32x4 accX[4][4] = {};
    f32x4 accY[4][4] = {};

    for (int kt = 0; kt < D_X / 64; ++kt) {
        __syncthreads();
        stage_tile_fb(x, D_X, iA, kt * 64, As, tid);
        stage_tile_fb(x, D_X, iB, kt * 64, Bs, tid);
        __syncthreads();
        mfma_step(As, Bs, wr, wc, lrow, kgrp, accX);
    }
    for (int kt = 0; kt < D_Y / 64; ++kt) {
        __syncthreads();
        stage_tile_fb(y, D_Y, iA, kt * 64, As, tid);
        stage_tile_fb(y, D_Y, iB, kt * 64, Bs, tid);
        __syncthreads();
        mfma_step(As, Bs, wr, wc, lrow, kgrp, accY);
    }

    float local = 0.f;
#pragma unroll
    for (int m = 0; m < 4; ++m) {
#pragma unroll
        for (int n = 0; n < 4; ++n) {
            int col   = wc * 64 + n * 16 + lrow;
            float sxj = snxB[col];
            float syj = snyB[col];
#pragma unroll
            for (int r = 0; r < 4; ++r) {
                int rowi  = wr * 64 + m * 16 + kgrp * 4 + r;
                float d2x = snxA[rowi] + sxj - 2.f * accX[m][n][r];
                float dxv = sqrtf(fmaxf(d2x, 1e-12f));
                float d2y = snyA[rowi] + syj - 2.f * accY[m][n][r];
                float dyv = sqrtf(fmaxf(d2y, 1e-12f));
                int gi = iA + rowi, gj = iB + col;
                bool keep = (gi != gj) && (dxv <= EPS_THR);
                float contrib = __expf(-dxv * SIGMA_INV) * dyv;
                local += keep ? contrib : 0.f;
            }
        }
    }
    if (bi != bj) local *= 2.f;

#pragma unroll
    for (int off = 32; off > 0; off >>= 1)
        local += __shfl_down(local, off, 64);
    if (lane == 0) wsum[wid] = local;
    __syncthreads();
    if (tid == 0)
        atomicAdd(out, wsum[0] + wsum[1] + wsum[2] + wsum[3]);
}

// ===========================================================================
extern "C" void kernel_launch(void* const* d_in, const int* in_sizes, int n_in,
                              void* d_out, int out_size, void* d_ws, size_t ws_size,
                              hipStream_t stream) {
    const float* x = (const float*)d_in[0];
    const float* y = (const float*)d_in[1];
    float* out = (float*)d_out;

    hipMemsetAsync(d_out, 0, sizeof(float) * (size_t)out_size, stream);

    const size_t xb_bytes = (size_t)BATCH * XSLOTS * 16;   // 8 MB
    const size_t yb_bytes = (size_t)BATCH * YSLOTS * 16;   // 4 MB
    const size_t need = xb_bytes + yb_bytes + 2 * (size_t)BATCH * sizeof(float);

    if (ws_size >= need) {
        u16x8* xb  = (u16x8*)d_ws;
        u16x8* yb  = (u16x8*)((char*)d_ws + xb_bytes);
        float* sqx = (float*)((char*)d_ws + xb_bytes + yb_bytes);
        float* sqy = sqx + BATCH;
        convert_kernel<<<BATCH, 192, 0, stream>>>(x, y, xb, yb, sqx, sqy);
        graph_loss_bf16<<<NBLK, 256, 0, stream>>>(xb, yb, sqx, sqy, out);
    } else {
        float* sqx = (float*)d_ws;
        float* sqy = sqx + BATCH;
        norms_kernel_fb<<<BATCH, 64, 0, stream>>>(x, y, sqx, sqy);
        graph_loss_fb<<<NBLK, 256, 0, stream>>>(x, y, sqx, sqy, out);
    }
}